// Round 1
// baseline (767.391 us; speedup 1.0000x reference)
//
#include <hip/hip_runtime.h>

#define E_TOTAL 1600000
#define ND 64
#define ED 32
#define IN_DIM 160
#define HID 128
#define OUTD 64

#define TM 128          // edges per block
#define A_STRIDE 168    // padded bf16 stride for A tile (2-way max bank aliasing)
#define H_STRIDE 136    // padded bf16 stride for h tile

typedef short v8s __attribute__((ext_vector_type(8)));
typedef float v4f __attribute__((ext_vector_type(4)));

__device__ __forceinline__ unsigned short f2bf(float f) {
    union { float f; unsigned u; } v; v.f = f;
    unsigned u = v.u;
    u += 0x7FFFu + ((u >> 16) & 1u);   // RNE
    return (unsigned short)(u >> 16);
}

// ---- prep: W1 [160x128] -> W1^T bf16 [128][160]; W2 [128x64] -> W2^T bf16 [64][128]
__global__ void prep_weights(const float* __restrict__ W1, const float* __restrict__ W2,
                             unsigned short* __restrict__ w1t, unsigned short* __restrict__ w2t) {
    int i = blockIdx.x * blockDim.x + threadIdx.x;
    if (i < IN_DIM * HID) {
        int n = i / IN_DIM, k = i % IN_DIM;
        w1t[i] = f2bf(W1[k * HID + n]);
    } else {
        int j = i - IN_DIM * HID;
        if (j < HID * OUTD) {
            int n = j / HID, k = j % HID;
            w2t[j] = f2bf(W2[k * OUTD + n]);
        }
    }
}

__global__ __launch_bounds__(256) void edge_mlp(
    const float* __restrict__ x, const float* __restrict__ ea,
    const float* __restrict__ b1, const float* __restrict__ b2,
    const int* __restrict__ eidx,
    const unsigned short* __restrict__ w1t, const unsigned short* __restrict__ w2t,
    float* __restrict__ out)
{
    __shared__ unsigned short Alds[TM * A_STRIDE];   // 43008 B; reused for h tile

    const int tid = threadIdx.x;
    const int e0 = blockIdx.x * TM;

    // ---- stage A tile: [x[src] | x[tgt] | edge_attr] as bf16, 2 threads/edge ----
    {
        const int p = tid >> 1;        // edge within tile
        const int half = tid & 1;      // 0: src+ea[0:16), 1: tgt+ea[16:32)
        const int e = e0 + p;
        const int node = eidx[half * E_TOTAL + e];
        const float4* xr = (const float4*)(x + (long)node * ND);
        unsigned short* arow = &Alds[p * A_STRIDE + half * ND];
#pragma unroll
        for (int k = 0; k < 16; ++k) {
            float4 f = xr[k];
            ushort4 s; s.x = f2bf(f.x); s.y = f2bf(f.y); s.z = f2bf(f.z); s.w = f2bf(f.w);
            *(ushort4*)(arow + 4 * k) = s;
        }
        const float4* er = (const float4*)(ea + (long)e * ED + half * 16);
        unsigned short* arow2 = &Alds[p * A_STRIDE + 2 * ND + half * 16];
#pragma unroll
        for (int k = 0; k < 4; ++k) {
            float4 f = er[k];
            ushort4 s; s.x = f2bf(f.x); s.y = f2bf(f.y); s.z = f2bf(f.z); s.w = f2bf(f.w);
            *(ushort4*)(arow2 + 4 * k) = s;
        }
    }
    __syncthreads();

    const int w = tid >> 6;
    const int lane = tid & 63;
    const int q = lane >> 4;       // quad 0..3
    const int c = lane & 15;
    const int wr = w >> 1, wc = w & 1;   // wave quadrant in 128x128 C1

    // ---- GEMM1: C1[128x128] = A[128x160] * W1, wave does 64x64 ----
    v4f acc[4][4] = {};
#pragma unroll
    for (int kk = 0; kk < 5; ++kk) {
        const int kb = kk * 32 + q * 8;
        v8s a[4], b[4];
#pragma unroll
        for (int i = 0; i < 4; ++i)
            a[i] = *(const v8s*)&Alds[(wr * 64 + i * 16 + c) * A_STRIDE + kb];
#pragma unroll
        for (int j = 0; j < 4; ++j)
            b[j] = *(const v8s*)&w1t[(wc * 64 + j * 16 + c) * IN_DIM + kb];
#pragma unroll
        for (int i = 0; i < 4; ++i)
#pragma unroll
            for (int j = 0; j < 4; ++j)
                acc[i][j] = __builtin_amdgcn_mfma_f32_16x16x32_bf16(a[i], b[j], acc[i][j], 0, 0, 0);
    }
    __syncthreads();   // all A reads complete before overwrite with h

    // ---- epilogue1: h = relu(C1 + b1) -> bf16 into reused LDS (stride 136) ----
#pragma unroll
    for (int j = 0; j < 4; ++j) {
        const int col = wc * 64 + j * 16 + c;
        const float bias = b1[col];
#pragma unroll
        for (int i = 0; i < 4; ++i) {
            const int rbase = wr * 64 + i * 16 + q * 4;
#pragma unroll
            for (int r = 0; r < 4; ++r) {
                float v = acc[i][j][r] + bias;
                v = v > 0.f ? v : 0.f;
                Alds[(rbase + r) * H_STRIDE + col] = f2bf(v);
            }
        }
    }
    __syncthreads();

    // ---- GEMM2: C2[128x64] = h[128x128] * W2, wave does 64x32 ----
    v4f acc2[4][2] = {};
#pragma unroll
    for (int kk = 0; kk < 4; ++kk) {
        const int kb = kk * 32 + q * 8;
        v8s a[4], b[2];
#pragma unroll
        for (int i = 0; i < 4; ++i)
            a[i] = *(const v8s*)&Alds[(wr * 64 + i * 16 + c) * H_STRIDE + kb];
#pragma unroll
        for (int j = 0; j < 2; ++j)
            b[j] = *(const v8s*)&w2t[(wc * 32 + j * 16 + c) * HID + kb];
#pragma unroll
        for (int i = 0; i < 4; ++i)
#pragma unroll
            for (int j = 0; j < 2; ++j)
                acc2[i][j] = __builtin_amdgcn_mfma_f32_16x16x32_bf16(a[i], b[j], acc2[i][j], 0, 0, 0);
    }

    // ---- epilogue2: out = C2 + b2 (fp32 global) ----
#pragma unroll
    for (int j = 0; j < 2; ++j) {
        const int o = wc * 32 + j * 16 + c;
        const float bias = b2[o];
#pragma unroll
        for (int i = 0; i < 4; ++i) {
            const int rbase = wr * 64 + i * 16 + q * 4;
#pragma unroll
            for (int r = 0; r < 4; ++r) {
                const long e = (long)e0 + rbase + r;
                out[e * OUTD + o] = acc2[i][j][r] + bias;
            }
        }
    }
}

extern "C" void kernel_launch(void* const* d_in, const int* in_sizes, int n_in,
                              void* d_out, int out_size, void* d_ws, size_t ws_size,
                              hipStream_t stream) {
    const float* x  = (const float*)d_in[0];
    const float* ea = (const float*)d_in[1];
    const float* W1 = (const float*)d_in[2];
    const float* b1 = (const float*)d_in[3];
    const float* W2 = (const float*)d_in[4];
    const float* b2 = (const float*)d_in[5];
    const int* eidx = (const int*)d_in[6];
    float* out = (float*)d_out;

    unsigned short* w1t = (unsigned short*)d_ws;            // 20480 bf16
    unsigned short* w2t = w1t + IN_DIM * HID;               // 8192 bf16 (16B-aligned offset)

    prep_weights<<<(IN_DIM * HID + HID * OUTD + 255) / 256, 256, 0, stream>>>(W1, W2, w1t, w2t);
    edge_mlp<<<E_TOTAL / TM, 256, 0, stream>>>(x, ea, b1, b2, eidx, w1t, w2t, out);
}

// Round 2
// 735.137 us; speedup vs baseline: 1.0439x; 1.0439x over previous
//
#include <hip/hip_runtime.h>

#define E_TOTAL 1600000
#define N_NODES 100000
#define ND 64
#define ED 32
#define IN_DIM 160
#define HID 128
#define OUTD 64

#define TM 128          // edges per block
#define H_STRIDE 136    // padded bf16 stride for h tile (row = 272 B, 16B-aligned)

typedef short v8s __attribute__((ext_vector_type(8)));
typedef float v4f __attribute__((ext_vector_type(4)));

__device__ __forceinline__ unsigned short f2bf(float f) {
    union { float f; unsigned u; } v; v.f = f;
    unsigned u = v.u;
    u += 0x7FFFu + ((u >> 16) & 1u);   // RNE
    return (unsigned short)(u >> 16);
}

__device__ __forceinline__ v8s cvt8(float4 f0, float4 f1) {
    v8s r;
    r[0] = (short)f2bf(f0.x); r[1] = (short)f2bf(f0.y);
    r[2] = (short)f2bf(f0.z); r[3] = (short)f2bf(f0.w);
    r[4] = (short)f2bf(f1.x); r[5] = (short)f2bf(f1.y);
    r[6] = (short)f2bf(f1.z); r[7] = (short)f2bf(f1.w);
    return r;
}

// ---- prep: x -> bf16 (row-major, 128 B/node) ----
__global__ void prep_x(const float* __restrict__ x, unsigned short* __restrict__ xbf) {
    int i = blockIdx.x * blockDim.x + threadIdx.x;
    if (i < N_NODES * ND) xbf[i] = f2bf(x[i]);
}

// ---- prep: W1/W2 -> bf16 in exact MFMA B-fragment order ----
// w1f[((kk*8 + jt)*64 + lane)*8 + t] = W1[k][n], n=jt*16+(lane&15), k=kk*32+(lane>>4)*8+t
// w2f[((kk*4 + jt)*64 + lane)*8 + t] = W2[k][n], same decomposition
__global__ void prep_weights(const float* __restrict__ W1, const float* __restrict__ W2,
                             unsigned short* __restrict__ w1f, unsigned short* __restrict__ w2f) {
    int i = blockIdx.x * blockDim.x + threadIdx.x;
    if (i < IN_DIM * HID) {
        int t8 = i & 7, lane = (i >> 3) & 63, jk = i >> 9;
        int kk = jk >> 3, jt = jk & 7, cc = lane & 15, qq = lane >> 4;
        int n = jt * 16 + cc, k = kk * 32 + qq * 8 + t8;
        w1f[i] = f2bf(W1[k * HID + n]);
    } else if (i < IN_DIM * HID + HID * OUTD) {
        int u = i - IN_DIM * HID;
        int t8 = u & 7, lane = (u >> 3) & 63, jk = u >> 9;
        int kk = jk >> 2, jt = jk & 3, cc = lane & 15, qq = lane >> 4;
        int n = jt * 16 + cc, k = kk * 32 + qq * 8 + t8;
        w2f[u] = f2bf(W2[k * OUTD + n]);
    }
}

template<bool XBF>
__global__ __launch_bounds__(256, 4) void edge_mlp(
    const float* __restrict__ x, const unsigned short* __restrict__ xbf,
    const float* __restrict__ ea,
    const float* __restrict__ b1, const float* __restrict__ b2,
    const int* __restrict__ eidx,
    const unsigned short* __restrict__ w1f, const unsigned short* __restrict__ w2f,
    float* __restrict__ out)
{
    __shared__ unsigned short h[TM * H_STRIDE];   // 34816 B -> 4 blocks/CU

    const int tid = threadIdx.x, lane = tid & 63, w = tid >> 6;
    const int wr = w >> 1, wc = w & 1, c = lane & 15, q = lane >> 4;
    const int e0 = blockIdx.x * TM;

    // this lane's 4 edge rows (m = lane&15 within each 16-row tile)
    int eRow[4], srcOff[4], tgtOff[4];
#pragma unroll
    for (int i = 0; i < 4; ++i) {
        eRow[i] = e0 + wr * 64 + i * 16 + c;
        srcOff[i] = eidx[eRow[i]] * ND;
        tgtOff[i] = eidx[E_TOTAL + eRow[i]] * ND;
    }

    // ---- GEMM1: C1[128x128], wave quadrant 64x64; A gathered direct-to-register ----
    v4f acc[4][4] = {};
#pragma unroll
    for (int kk = 0; kk < 5; ++kk) {
        v8s a[4];
#pragma unroll
        for (int i = 0; i < 4; ++i) {
            if (kk < 4) {
                const int off = (kk < 2 ? srcOff[i] : tgtOff[i]) + (kk & 1) * 32 + q * 8;
                if (XBF) {
                    a[i] = *(const v8s*)(xbf + off);
                } else {
                    const float4* p = (const float4*)(x + off);
                    a[i] = cvt8(p[0], p[1]);
                }
            } else {
                const float4* p = (const float4*)(ea + (long)eRow[i] * ED + q * 8);
                a[i] = cvt8(p[0], p[1]);
            }
        }
        v8s b[4];
#pragma unroll
        for (int j = 0; j < 4; ++j)
            b[j] = *(const v8s*)(w1f + ((kk * 8 + wc * 4 + j) * 64 + lane) * 8);
#pragma unroll
        for (int i = 0; i < 4; ++i)
#pragma unroll
            for (int j = 0; j < 4; ++j)
                acc[i][j] = __builtin_amdgcn_mfma_f32_16x16x32_bf16(a[i], b[j], acc[i][j], 0, 0, 0);
    }

    // ---- epilogue1: h = relu(C1 + b1) -> bf16 LDS ----
#pragma unroll
    for (int j = 0; j < 4; ++j) {
        const float bias = b1[wc * 64 + j * 16 + c];
#pragma unroll
        for (int i = 0; i < 4; ++i) {
#pragma unroll
            for (int r = 0; r < 4; ++r) {
                float v = acc[i][j][r] + bias;
                v = v > 0.f ? v : 0.f;
                h[(wr * 64 + i * 16 + q * 4 + r) * H_STRIDE + wc * 64 + j * 16 + c] = f2bf(v);
            }
        }
    }
    __syncthreads();

    // ---- GEMM2: C2[128x64] = h * W2, wave does 64x32 ----
    v4f acc2[4][2] = {};
#pragma unroll
    for (int kk = 0; kk < 4; ++kk) {
        v8s a[4];
#pragma unroll
        for (int i = 0; i < 4; ++i)
            a[i] = *(const v8s*)(h + (wr * 64 + i * 16 + c) * H_STRIDE + kk * 32 + q * 8);
        v8s b[2];
#pragma unroll
        for (int j = 0; j < 2; ++j)
            b[j] = *(const v8s*)(w2f + ((kk * 4 + wc * 2 + j) * 64 + lane) * 8);
#pragma unroll
        for (int i = 0; i < 4; ++i)
#pragma unroll
            for (int j = 0; j < 2; ++j)
                acc2[i][j] = __builtin_amdgcn_mfma_f32_16x16x32_bf16(a[i], b[j], acc2[i][j], 0, 0, 0);
    }

    // ---- epilogue2: out = C2 + b2 (fp32) ----
#pragma unroll
    for (int j = 0; j < 2; ++j) {
        const float bias = b2[wc * 32 + j * 16 + c];
#pragma unroll
        for (int i = 0; i < 4; ++i) {
#pragma unroll
            for (int r = 0; r < 4; ++r) {
                const long e = (long)e0 + wr * 64 + i * 16 + q * 4 + r;
                out[e * OUTD + wc * 32 + j * 16 + c] = acc2[i][j][r] + bias;
            }
        }
    }
}

extern "C" void kernel_launch(void* const* d_in, const int* in_sizes, int n_in,
                              void* d_out, int out_size, void* d_ws, size_t ws_size,
                              hipStream_t stream) {
    const float* x  = (const float*)d_in[0];
    const float* ea = (const float*)d_in[1];
    const float* W1 = (const float*)d_in[2];
    const float* b1 = (const float*)d_in[3];
    const float* W2 = (const float*)d_in[4];
    const float* b2 = (const float*)d_in[5];
    const int* eidx = (const int*)d_in[6];
    float* out = (float*)d_out;

    const size_t nx = (size_t)N_NODES * ND;                          // 6.4M bf16
    const size_t need = (nx + IN_DIM * HID + HID * OUTD) * 2;        // ~12.86 MB
    const int nw = IN_DIM * HID + HID * OUTD;                        // 28672 weight elems

    if (ws_size >= need) {
        unsigned short* xbf = (unsigned short*)d_ws;
        unsigned short* w1f = xbf + nx;
        unsigned short* w2f = w1f + IN_DIM * HID;
        prep_x<<<(int)((nx + 255) / 256), 256, 0, stream>>>(x, xbf);
        prep_weights<<<(nw + 255) / 256, 256, 0, stream>>>(W1, W2, w1f, w2f);
        edge_mlp<true><<<E_TOTAL / TM, 256, 0, stream>>>(x, xbf, ea, b1, b2, eidx, w1f, w2f, out);
    } else {
        unsigned short* w1f = (unsigned short*)d_ws;
        unsigned short* w2f = w1f + IN_DIM * HID;
        prep_weights<<<(nw + 255) / 256, 256, 0, stream>>>(W1, W2, w1f, w2f);
        edge_mlp<false><<<E_TOTAL / TM, 256, 0, stream>>>(x, nullptr, ea, b1, b2, eidx, w1f, w2f, out);
    }
}